// Round 2
// baseline (248.442 us; speedup 1.0000x reference)
//
#include <hip/hip_runtime.h>

// MAMBA chunk scan, fused K=384 bf16 MFMA GEMM per (b,c,h):
//   out[m,p] = exp(dA[m]) * ( C[m,:]@prev[p,:]^T
//             + sum_{k<=m} cb[m,k]*exp(-dA[k])*dt[k]*x[k,p] + diag D*exp(-dA[m]) )
// Round 2: M-split x2 (grid 2048, 128 rows/block), register prefetch of next
// tile's global loads, LDS double-buffer (1 barrier/iter), causal tile skip
// (half=0 runs 8 K-tiles, not 12) and per-m-subtile MFMA skip.
// B=2 S=4096 CS=256 H=32 G=1 P=64 N=128 NC=16

typedef unsigned short u16;
typedef __bf16 v8bf __attribute__((ext_vector_type(8)));
typedef unsigned short v8u16 __attribute__((ext_vector_type(8)));
typedef float v4f __attribute__((ext_vector_type(4)));

#define LDA 40  // LDS row stride (bf16): 80B, 16B-aligned rows
#define LDB 40

__device__ __forceinline__ u16 f2bf(float f) {
  unsigned u = __builtin_bit_cast(unsigned, f);
  unsigned r = u + 0x7FFFu + ((u >> 16) & 1u);  // RNE
  return (u16)(r >> 16);
}
__device__ __forceinline__ unsigned pk2(float a, float b) {
  return (unsigned)f2bf(a) | ((unsigned)f2bf(b) << 16);
}

__global__ __launch_bounds__(256, 4) void mamba_cs_kernel(
    const float* __restrict__ cbp,   // (2,16,1,256,256)
    const float* __restrict__ xp,    // (2,4096,32,64)
    const float* __restrict__ dtp,   // (2,32,16,256)
    const float* __restrict__ dAp,   // (2,32,16,256)
    const float* __restrict__ Cp,    // (2,4096,1,128)
    const float* __restrict__ pvp,   // (2,16,32,64,128)
    const float* __restrict__ Dp,    // (32,)
    float* __restrict__ outp)        // (2,4096,32,64)
{
  __shared__ u16 sA[2][128 * LDA];   // 20.5 KB
  __shared__ u16 sB[2][64 * LDB];    // 10.25 KB
  __shared__ float s_edm[256];   // exp(dA[m])
  __shared__ float s_w[256];     // exp(-dA[k]) * dt[k]
  __shared__ float s_winv[256];  // exp(-dA[m])

  const int bid = blockIdx.x;
  const int h = bid & 31;
  const int half = (bid >> 5) & 1;
  const int c = (bid >> 6) & 15;
  const int b = bid >> 10;
  const int t = threadIdx.x;
  const int lane = t & 63;
  const int wid = t >> 6;
  const int m0 = half * 128;

  // ---- prologue: decay factors for the whole chunk ----
  {
    const int base = ((b * 32 + h) * 16 + c) * 256 + t;
    float dAv = dAp[base];
    float dtv = dtp[base];
    s_edm[t] = __expf(dAv);
    float wi = __expf(-dAv);
    s_winv[t] = wi;
    s_w[t] = wi * dtv;
  }
  const float Dh = Dp[h];

  v4f acc[2][4];
#pragma unroll
  for (int i = 0; i < 2; i++)
#pragma unroll
    for (int j = 0; j < 4; j++) acc[i][j] = (v4f){0.f, 0.f, 0.f, 0.f};

  const float* Cbase = Cp + (size_t)(b * 4096 + c * 256) * 128;
  const float* Pbase = pvp + (size_t)((b * 16 + c) * 32 + h) * 64 * 128;
  const float* CBbase = cbp + (size_t)(b * 16 + c) * 65536;
  const float* Xbase = xp + ((size_t)(b * 4096 + c * 256) * 32 + h) * 64;  // row stride 2048

  // tiles: kt<4 -> inter (n0=kt*32); kt>=4 -> intra (k0=(kt-4)*32)
  // half=0 only needs intra k0<=96 (causality) -> 8 tiles total
  const int nkt = half ? 12 : 8;

  float4 pa[4];   // A-tile prefetch: 128x32 fp32 = 1024 f4 / 256 thr
  float pxb[8];   // B-tile prefetch: inter 2xfloat4, intra 8 scalars

  auto load_tile = [&](int kt) {
    if (kt < 4) {
      const int n0 = kt * 32;
#pragma unroll
      for (int i = 0; i < 4; i++) {
        int v = t + i * 256, r = v >> 3, co = (v & 7) * 4;
        pa[i] = *(const float4*)(Cbase + (size_t)(m0 + r) * 128 + n0 + co);
      }
#pragma unroll
      for (int i = 0; i < 2; i++) {
        int v = t + i * 256, p = v >> 3, no = (v & 7) * 4;
        ((float4*)pxb)[i] = *(const float4*)(Pbase + (size_t)p * 128 + n0 + no);
      }
    } else {
      const int k0 = (kt - 4) * 32;
#pragma unroll
      for (int i = 0; i < 4; i++) {
        int v = t + i * 256, r = v >> 3, co = (v & 7) * 4;
        pa[i] = *(const float4*)(CBbase + (size_t)(m0 + r) * 256 + k0 + co);
      }
      const int kp = t >> 4, pg = t & 15;
      const float* xr0 = Xbase + (size_t)(k0 + 2 * kp) * 2048;
      const float* xr1 = xr0 + 2048;
#pragma unroll
      for (int j = 0; j < 4; j++) {
        pxb[2 * j] = xr0[pg + 16 * j];
        pxb[2 * j + 1] = xr1[pg + 16 * j];
      }
    }
  };

  auto store_tile = [&](int kt, int buf) {
    if (kt < 4) {
#pragma unroll
      for (int i = 0; i < 4; i++) {
        int v = t + i * 256, r = v >> 3, co = (v & 7) * 4;
        uint2 d = make_uint2(pk2(pa[i].x, pa[i].y), pk2(pa[i].z, pa[i].w));
        *(uint2*)&sA[buf][r * LDA + co] = d;
      }
#pragma unroll
      for (int i = 0; i < 2; i++) {
        int v = t + i * 256, p = v >> 3, no = (v & 7) * 4;
        float4 f = ((float4*)pxb)[i];
        *(uint2*)&sB[buf][p * LDB + no] = make_uint2(pk2(f.x, f.y), pk2(f.z, f.w));
      }
    } else {
      const int k0 = (kt - 4) * 32;
#pragma unroll
      for (int i = 0; i < 4; i++) {
        int v = t + i * 256, r = v >> 3, co = (v & 7) * 4;
        const int m = m0 + r;
        float vals[4] = {pa[i].x, pa[i].y, pa[i].z, pa[i].w};
        u16 o[4];
#pragma unroll
        for (int j = 0; j < 4; j++) {
          int k = k0 + co + j;
          float val = (k <= m) ? vals[j] * s_w[k] : 0.f;
          if (k == m) val += Dh * s_winv[m];
          o[j] = f2bf(val);
        }
        uint2 d = make_uint2((unsigned)o[0] | ((unsigned)o[1] << 16),
                             (unsigned)o[2] | ((unsigned)o[3] << 16));
        *(uint2*)&sA[buf][r * LDA + co] = d;
      }
      const int kp = t >> 4, pg = t & 15;
#pragma unroll
      for (int j = 0; j < 4; j++) {
        int p = pg + 16 * j;
        *(unsigned*)&sB[buf][p * LDB + 2 * kp] = pk2(pxb[2 * j], pxb[2 * j + 1]);
      }
    }
  };

  auto compute = [&](int kt, int buf) {
    const int row = lane & 15;
    const int koff = (lane >> 4) * 8;
    const int k0 = (kt >= 4) ? (kt - 4) * 32 : -1000;
    v8bf bfrag[4];
#pragma unroll
    for (int pt = 0; pt < 4; ++pt)
      bfrag[pt] = __builtin_bit_cast(v8bf, *(const v8u16*)&sB[buf][(pt * 16 + row) * LDB + koff]);
#pragma unroll
    for (int mt = 0; mt < 2; ++mt) {
      const int ms = m0 + wid * 32 + mt * 16;
      if (k0 > ms + 15) continue;  // intra tile entirely above diagonal: A rows all zero
      v8bf afrag = __builtin_bit_cast(
          v8bf, *(const v8u16*)&sA[buf][(wid * 32 + mt * 16 + row) * LDA + koff]);
#pragma unroll
      for (int pt = 0; pt < 4; ++pt)
        acc[mt][pt] = __builtin_amdgcn_mfma_f32_16x16x32_bf16(afrag, bfrag[pt],
                                                              acc[mt][pt], 0, 0, 0);
    }
  };

  load_tile(0);
  store_tile(0, 0);
  __syncthreads();
  for (int kt = 0; kt < nkt; ++kt) {
    const int cur = kt & 1;
    if (kt + 1 < nkt) load_tile(kt + 1);   // global loads in flight during MFMA
    compute(kt, cur);
    if (kt + 1 < nkt) store_tile(kt + 1, cur ^ 1);  // waits vmcnt, writes other buffer
    __syncthreads();
  }

  // ---- epilogue: scale by exp(dA[m]) and store ----
  // C/D layout: col = lane&15, row = (lane>>4)*4 + reg
  float* Obase = outp + ((size_t)(b * 4096 + c * 256) * 32 + h) * 64;
  const int col = lane & 15;
  const int rbase = (lane >> 4) * 4;
#pragma unroll
  for (int mt = 0; mt < 2; ++mt) {
#pragma unroll
    for (int r = 0; r < 4; ++r) {
      const int m = m0 + wid * 32 + mt * 16 + rbase + r;
      const float e = s_edm[m];
      float* orow = Obase + (size_t)m * 2048;
#pragma unroll
      for (int pt = 0; pt < 4; ++pt)
        orow[pt * 16 + col] = acc[mt][pt][r] * e;
    }
  }
}

extern "C" void kernel_launch(void* const* d_in, const int* in_sizes, int n_in,
                              void* d_out, int out_size, void* d_ws, size_t ws_size,
                              hipStream_t stream) {
  const float* cb = (const float*)d_in[0];
  const float* x = (const float*)d_in[1];
  const float* dt = (const float*)d_in[2];
  const float* dA = (const float*)d_in[3];
  const float* C = (const float*)d_in[4];
  const float* pv = (const float*)d_in[5];
  const float* D = (const float*)d_in[6];
  float* out = (float*)d_out;
  // grid 2048: h fastest (cb/C L2 reuse), then M-half (x/prev reuse), then c, b
  mamba_cs_kernel<<<dim3(2048), dim3(256), 0, stream>>>(cb, x, dt, dA, C, pv, D, out);
}

// Round 3
// 238.218 us; speedup vs baseline: 1.0429x; 1.0429x over previous
//
#include <hip/hip_runtime.h>

// MAMBA chunk scan, fused K=384 bf16 MFMA GEMM per (b,c,h, m-half):
//   out[m,p] = exp(dA[m]) * ( C[m,:]@prev[p,:]^T                      (inter, K=128)
//             + sum_{k<=m} cb[m,k]*exp(-dA[k])*dt[k]*x[k,p]           (intra, K=256)
//             + diag: D[h]*exp(-dA[m]) )
// Round 3: K=128 mega-tiles -> 2 iters (half=0) / 3 iters (half=1) instead of
// 12 K32 tiles: one vmcnt latency exposure per iter with ~24 loads in flight.
// No launch_bounds VGPR cap (round-2 spilled: WRITE_SIZE +37MB, VGPR=64).
// Decay factors recomputed per-thread from global dA/dt (no LDS arrays) ->
// LDS 52.2KB -> 3 blocks/CU. Row stride 136 u16 = 272B: all ds_read_b128
// fragment reads and staging writes verified at the bank-conflict floor.
// B=2 S=4096 CS=256 H=32 G=1 P=64 N=128 NC=16

typedef unsigned short u16;
typedef __bf16 v8bf __attribute__((ext_vector_type(8)));
typedef unsigned short v8u16 __attribute__((ext_vector_type(8)));
typedef float v4f __attribute__((ext_vector_type(4)));

#define LDA 136  // u16 units; 272B row stride, 16B-aligned rows
#define LDB 136

__device__ __forceinline__ u16 f2bf(float f) {
  unsigned u = __builtin_bit_cast(unsigned, f);
  unsigned r = u + 0x7FFFu + ((u >> 16) & 1u);  // RNE
  return (u16)(r >> 16);
}
__device__ __forceinline__ unsigned pk2(float a, float b) {
  return (unsigned)f2bf(a) | ((unsigned)f2bf(b) << 16);
}

__global__ __launch_bounds__(256) void mamba_cs_kernel(
    const float* __restrict__ cbp,   // (2,16,1,256,256)
    const float* __restrict__ xp,    // (2,4096,32,64)
    const float* __restrict__ dtp,   // (2,32,16,256)
    const float* __restrict__ dAp,   // (2,32,16,256)
    const float* __restrict__ Cp,    // (2,4096,1,128)
    const float* __restrict__ pvp,   // (2,16,32,64,128)
    const float* __restrict__ Dp,    // (32,)
    float* __restrict__ outp)        // (2,4096,32,64)
{
  __shared__ u16 sA[128 * LDA];  // 34816 B
  __shared__ u16 sB[64 * LDB];   // 17408 B   (total 52224 B -> 3 blocks/CU)

  const int bid = blockIdx.x;
  const int h = bid & 31;
  const int half = (bid >> 5) & 1;
  const int c = (bid >> 6) & 15;
  const int b = bid >> 10;
  const int t = threadIdx.x;
  const int lane = t & 63;
  const int wid = t >> 6;
  const int m0 = half * 128;

  // staging thread mapping: 32 lanes cover one 512B row (co fixed across i)
  const int co = (t & 31) * 4;  // column (floats), 0..124
  const int r0 = t >> 5;        // row base; rows r0 + 8*i
  const int kp = t >> 4, pg = t & 15;  // x-transpose mapping

  const int base_hc = ((b * 32 + h) * 16 + c) * 256;
  const float Dh = Dp[h];

  v4f acc[2][4];
#pragma unroll
  for (int i = 0; i < 2; i++)
#pragma unroll
    for (int j = 0; j < 4; j++) acc[i][j] = (v4f){0.f, 0.f, 0.f, 0.f};

  const float* Cbase = Cp + (size_t)(b * 4096 + c * 256) * 128;
  const float* Pbase = pvp + (size_t)((b * 16 + c) * 32 + h) * 8192;
  const float* CBbase = cbp + (size_t)(b * 16 + c) * 65536;
  const float* Xbase = xp + ((size_t)(b * 4096 + c * 256) * 32 + h) * 64;  // row stride 2048

  // iter 0: inter (n=0..127); iter kt>=1: intra k_base=(kt-1)*128
  // half=0 needs no intra k>=128 (causality) -> 2 iters; half=1 -> 3 iters
  const int nkt = half ? 3 : 2;

  for (int kt = 0; kt < nkt; ++kt) {
    if (kt == 0) {
      // ---- stage inter: A = C[m0+ .. ][128], B = prev[p][128] ----
      float4 a0[8], bb[8];
#pragma unroll
      for (int i = 0; i < 8; i++)
        a0[i] = *(const float4*)(Cbase + (size_t)(m0 + r0 + 8 * i) * 128 + co);
#pragma unroll
      for (int i = 0; i < 8; i++)
        bb[i] = *(const float4*)(Pbase + (size_t)(r0 + 8 * i) * 128 + co);
#pragma unroll
      for (int i = 0; i < 8; i++)
        *(uint2*)&sA[(r0 + 8 * i) * LDA + co] =
            make_uint2(pk2(a0[i].x, a0[i].y), pk2(a0[i].z, a0[i].w));
      float4 a1[8];
#pragma unroll
      for (int i = 0; i < 8; i++)
        a1[i] = *(const float4*)(Cbase + (size_t)(m0 + 64 + r0 + 8 * i) * 128 + co);
#pragma unroll
      for (int i = 0; i < 8; i++)
        *(uint2*)&sB[(r0 + 8 * i) * LDB + co] =
            make_uint2(pk2(bb[i].x, bb[i].y), pk2(bb[i].z, bb[i].w));
#pragma unroll
      for (int i = 0; i < 8; i++)
        *(uint2*)&sA[(64 + r0 + 8 * i) * LDA + co] =
            make_uint2(pk2(a1[i].x, a1[i].y), pk2(a1[i].z, a1[i].w));
    } else {
      const int k_base = (kt - 1) * 128;
      // per-thread decay factors for its 4 k-columns (no LDS round trip)
      const float4 dA4 = *(const float4*)(dAp + base_hc + k_base + co);
      const float4 dt4 = *(const float4*)(dtp + base_hc + k_base + co);
      float wi[4], w[4];
      {
        const float da[4] = {dA4.x, dA4.y, dA4.z, dA4.w};
        const float dt_[4] = {dt4.x, dt4.y, dt4.z, dt4.w};
#pragma unroll
        for (int j = 0; j < 4; j++) {
          wi[j] = __expf(-da[j]);     // exp(-dA[k])
          w[j] = wi[j] * dt_[j];      // exp(-dA[k]) * dt[k]
        }
      }
      auto cvt_store = [&](const float4& f, int rr) {
        const int m = m0 + rr;
        const float vv[4] = {f.x, f.y, f.z, f.w};
        u16 o[4];
#pragma unroll
        for (int j = 0; j < 4; j++) {
          const int k = k_base + co + j;
          float val = (k <= m) ? vv[j] * w[j] : 0.f;
          if (k == m) val += Dh * wi[j];  // diag: D*exp(-dA[m]) (k==m so wi[j]=exp(-dA[m]))
          o[j] = f2bf(val);
        }
        *(uint2*)&sA[rr * LDA + co] =
            make_uint2((unsigned)o[0] | ((unsigned)o[1] << 16),
                       (unsigned)o[2] | ((unsigned)o[3] << 16));
      };
      // ---- stage intra: A = masked cb*w, B = x^T ----
      float4 a0[8];
#pragma unroll
      for (int i = 0; i < 8; i++)
        a0[i] = *(const float4*)(CBbase + (size_t)(m0 + r0 + 8 * i) * 256 + k_base + co);
      float xb[32];
#pragma unroll
      for (int kk = 0; kk < 4; kk++) {
        const float* xr0 = Xbase + (size_t)(k_base + kk * 32 + 2 * kp) * 2048;
        const float* xr1 = xr0 + 2048;
#pragma unroll
        for (int j = 0; j < 4; j++) {
          xb[kk * 8 + 2 * j] = xr0[pg + 16 * j];
          xb[kk * 8 + 2 * j + 1] = xr1[pg + 16 * j];
        }
      }
#pragma unroll
      for (int i = 0; i < 8; i++) cvt_store(a0[i], r0 + 8 * i);
      float4 a1[8];
#pragma unroll
      for (int i = 0; i < 8; i++)
        a1[i] = *(const float4*)(CBbase + (size_t)(m0 + 64 + r0 + 8 * i) * 256 + k_base + co);
#pragma unroll
      for (int kk = 0; kk < 4; kk++) {
        const int k2 = kk * 32 + 2 * kp;
#pragma unroll
        for (int j = 0; j < 4; j++)
          *(unsigned*)&sB[(pg + 16 * j) * LDB + k2] =
              pk2(xb[kk * 8 + 2 * j], xb[kk * 8 + 2 * j + 1]);
      }
#pragma unroll
      for (int i = 0; i < 8; i++) cvt_store(a1[i], 64 + r0 + 8 * i);
    }
    __syncthreads();

    // ---- compute: 4 K32 sub-steps from LDS, wave wid owns m rows [wid*32, wid*32+32) ----
    {
      const int row = lane & 15;
      const int q = lane >> 4;
      const int kb = (kt == 0) ? -1000000 : (kt - 1) * 128;
#pragma unroll
      for (int kf = 0; kf < 4; ++kf) {
        const int koff = kf * 32 + q * 8;
        const int ck0 = kb + kf * 32;
        v8bf bfrag[4];
#pragma unroll
        for (int pt = 0; pt < 4; ++pt)
          bfrag[pt] = __builtin_bit_cast(
              v8bf, *(const v8u16*)&sB[(pt * 16 + row) * LDB + koff]);
#pragma unroll
        for (int mt = 0; mt < 2; ++mt) {
          const int ms = m0 + wid * 32 + mt * 16;
          if (ck0 > ms + 15) continue;  // intra chunk fully above diagonal: A rows zero
          v8bf afrag = __builtin_bit_cast(
              v8bf, *(const v8u16*)&sA[(wid * 32 + mt * 16 + row) * LDA + koff]);
#pragma unroll
          for (int pt = 0; pt < 4; ++pt)
            acc[mt][pt] = __builtin_amdgcn_mfma_f32_16x16x32_bf16(afrag, bfrag[pt],
                                                                  acc[mt][pt], 0, 0, 0);
        }
      }
    }
    __syncthreads();
  }

  // ---- epilogue: scale by exp(dA[m]) and store ----
  // C/D layout: col = lane&15, row = (lane>>4)*4 + reg
  float* Obase = outp + ((size_t)(b * 4096 + c * 256) * 32 + h) * 64;
  const int col = lane & 15;
  const int rbase = (lane >> 4) * 4;
#pragma unroll
  for (int mt = 0; mt < 2; ++mt) {
#pragma unroll
    for (int r = 0; r < 4; ++r) {
      const int m = m0 + wid * 32 + mt * 16 + rbase + r;
      const float e = __expf(dAp[base_hc + m]);
      float* orow = Obase + (size_t)m * 2048;
#pragma unroll
      for (int pt = 0; pt < 4; ++pt)
        orow[pt * 16 + col] = acc[mt][pt][r] * e;
    }
  }
}

extern "C" void kernel_launch(void* const* d_in, const int* in_sizes, int n_in,
                              void* d_out, int out_size, void* d_ws, size_t ws_size,
                              hipStream_t stream) {
  const float* cb = (const float*)d_in[0];
  const float* x = (const float*)d_in[1];
  const float* dt = (const float*)d_in[2];
  const float* dA = (const float*)d_in[3];
  const float* C = (const float*)d_in[4];
  const float* pv = (const float*)d_in[5];
  const float* D = (const float*)d_in[6];
  float* out = (float*)d_out;
  // grid 2048: h fastest (cb/C L2 reuse), then m-half (x/prev reuse), then c, b
  mamba_cs_kernel<<<dim3(2048), dim3(256), 0, stream>>>(cb, x, dt, dA, C, pv, D, out);
}

// Round 4
// 228.768 us; speedup vs baseline: 1.0860x; 1.0413x over previous
//
#include <hip/hip_runtime.h>

// MAMBA chunk scan, fused K=384 bf16 MFMA GEMM per (b,c,h, m-half):
//   out[m,p] = exp(dA[m]) * ( C[m,:]@prev[p,:]^T                      (inter, K=128)
//             + sum_{k<=m} cb[m,k]*exp(-dA[k])*dt[k]*x[k,p]           (intra, K<=256)
//             + diag: D[h]*exp(-dA[m]) )
// Round 4: direct global->VGPR MFMA fragments for cb/C (A) and prev (inter B):
// a lane's A-fragment = 8 consecutive k elements = 2 float4 loads from the
// row-major input. No LDS staging / no barriers for 75% of bytes; mask+w[k]
// scaling applied per-lane in registers. Only x^T (true transpose) uses LDS
// (double-buffered, 35KB, both tiles' loads issued before the 1st barrier).
// Barriers: half0 1, half1 2 (was 5-6 pairs). Waves slip freely -> continuous
// MLP instead of batch-and-drain.
// B=2 S=4096 CS=256 H=32 G=1 P=64 N=128 NC=16

typedef unsigned short u16;
typedef __bf16 v8bf __attribute__((ext_vector_type(8)));
typedef unsigned short v8u16 __attribute__((ext_vector_type(8)));
typedef float v4f __attribute__((ext_vector_type(4)));

#define LDB 136  // u16; 272B row stride (16B-aligned, 2-way bank floor verified r3)

__device__ __forceinline__ unsigned pk2(float a, float b) {
  u16 x = __builtin_bit_cast(u16, (__bf16)a);
  u16 y = __builtin_bit_cast(u16, (__bf16)b);
  return (unsigned)x | ((unsigned)y << 16);
}
__device__ __forceinline__ v8bf cvt8(float4 lo, float4 hi) {
  v8bf r;
  r[0] = (__bf16)lo.x; r[1] = (__bf16)lo.y; r[2] = (__bf16)lo.z; r[3] = (__bf16)lo.w;
  r[4] = (__bf16)hi.x; r[5] = (__bf16)hi.y; r[6] = (__bf16)hi.z; r[7] = (__bf16)hi.w;
  return r;
}

__global__ __launch_bounds__(256) void mamba_cs_kernel(
    const float* __restrict__ cbp,   // (2,16,1,256,256)
    const float* __restrict__ xp,    // (2,4096,32,64)
    const float* __restrict__ dtp,   // (2,32,16,256)
    const float* __restrict__ dAp,   // (2,32,16,256)
    const float* __restrict__ Cp,    // (2,4096,1,128)
    const float* __restrict__ pvp,   // (2,16,32,64,128)
    const float* __restrict__ Dp,    // (32,)
    float* __restrict__ outp)        // (2,4096,32,64)
{
  __shared__ u16 sB[2][64 * LDB];  // x^T double buffer, 2x17408B

  const int bid = blockIdx.x;
  const int h = bid & 31;
  const int half = (bid >> 5) & 1;
  const int c = (bid >> 6) & 15;
  const int b = bid >> 10;
  const int t = threadIdx.x;
  const int lane = t & 63;
  const int wid = t >> 6;
  const int m0 = half * 128;

  const int row = lane & 15;
  const int q = lane >> 4;
  const int qo = q * 8;
  const int ws = m0 + wid * 32;       // wave's first m row
  const int m1 = ws + row;            // mt=0 lane row
  const int m2 = m1 + 16;             // mt=1 lane row

  const int base_hc = ((b * 32 + h) * 16 + c) * 256;
  const float Dh = Dp[h];

  const float* CBbase = cbp + (size_t)(b * 16 + c) * 65536;
  const float* Cbase = Cp + (size_t)(b * 4096 + c * 256) * 128;
  const float* Pbase = pvp + (size_t)((b * 16 + c) * 32 + h) * 8192;
  const float* Xbase = xp + ((size_t)(b * 4096 + c * 256) * 32 + h) * 64;  // k row stride 2048

  const float* cbr0 = CBbase + (size_t)m1 * 256;
  const float* cbr1 = CBbase + (size_t)m2 * 256;
  const float* Cr0 = Cbase + (size_t)m1 * 128;
  const float* Cr1 = Cbase + (size_t)m2 * 128;

  // x^T staging mapping (block-wide): thread handles k rows 2kp,2kp+1 (+32kk), p = pg+16j
  const int kp = t >> 4, pg = t & 15;

  v4f acc[2][4];
#pragma unroll
  for (int i = 0; i < 2; i++)
#pragma unroll
    for (int j = 0; j < 4; j++) acc[i][j] = (v4f){0.f, 0.f, 0.f, 0.f};

  auto xload = [&](int k_base, unsigned* xr) {
#pragma unroll
    for (int kk = 0; kk < 4; kk++) {
      const float* x0 = Xbase + (size_t)(k_base + kk * 32 + 2 * kp) * 2048;
      const float* x1 = x0 + 2048;
#pragma unroll
      for (int j = 0; j < 4; j++) {
        const int p = pg + 16 * j;
        xr[kk * 4 + j] = pk2(x0[p], x1[p]);  // packed (k, k+1) bf16 pair
      }
    }
  };
  auto xstore = [&](const unsigned* xr, int buf) {
#pragma unroll
    for (int kk = 0; kk < 4; kk++)
#pragma unroll
      for (int j = 0; j < 4; j++)
        *(unsigned*)&sB[buf][(pg + 16 * j) * LDB + kk * 32 + 2 * kp] = xr[kk * 4 + j];
  };

  auto intra = [&](int k_base, int buf) {
#pragma unroll
    for (int kf = 0; kf < 4; ++kf) {
      const int k0f = k_base + kf * 32;
      if (k0f > ws + 31) break;  // this wave fully above diagonal from here on
      const int ko = k0f + qo;   // lane's first k index
      // decay weights for lane's 8 k's (w = exp(-dA)*dt, wi = exp(-dA))
      const float4 dlo = *(const float4*)(dAp + base_hc + ko);
      const float4 dhi = *(const float4*)(dAp + base_hc + ko + 4);
      const float4 tlo = *(const float4*)(dtp + base_hc + ko);
      const float4 thi = *(const float4*)(dtp + base_hc + ko + 4);
      float wv[8], wiv[8];
      {
        const float dv[8] = {dlo.x, dlo.y, dlo.z, dlo.w, dhi.x, dhi.y, dhi.z, dhi.w};
        const float tv[8] = {tlo.x, tlo.y, tlo.z, tlo.w, thi.x, thi.y, thi.z, thi.w};
#pragma unroll
        for (int j = 0; j < 8; j++) {
          wiv[j] = __expf(-dv[j]);
          wv[j] = wiv[j] * tv[j];
        }
      }
      // B fragments from LDS (x^T)
      v8bf bf[4];
#pragma unroll
      for (int pt = 0; pt < 4; ++pt)
        bf[pt] = __builtin_bit_cast(
            v8bf, *(const v8u16*)&sB[buf][(pt * 16 + row) * LDB + kf * 32 + qo]);
      // A fragment mt=0 (direct from cb row), masked+scaled in regs
      if (k0f <= ws + 15) {
        const float4 alo = *(const float4*)(cbr0 + ko);
        const float4 ahi = *(const float4*)(cbr0 + ko + 4);
        const float av[8] = {alo.x, alo.y, alo.z, alo.w, ahi.x, ahi.y, ahi.z, ahi.w};
        v8bf a;
#pragma unroll
        for (int j = 0; j < 8; j++) {
          const int k = ko + j;
          float v = (k <= m1) ? av[j] * wv[j] : 0.f;
          if (k == m1) v += Dh * wiv[j];
          a[j] = (__bf16)v;
        }
#pragma unroll
        for (int pt = 0; pt < 4; ++pt)
          acc[0][pt] = __builtin_amdgcn_mfma_f32_16x16x32_bf16(a, bf[pt], acc[0][pt], 0, 0, 0);
      }
      // A fragment mt=1
      {
        const float4 alo = *(const float4*)(cbr1 + ko);
        const float4 ahi = *(const float4*)(cbr1 + ko + 4);
        const float av[8] = {alo.x, alo.y, alo.z, alo.w, ahi.x, ahi.y, ahi.z, ahi.w};
        v8bf a;
#pragma unroll
        for (int j = 0; j < 8; j++) {
          const int k = ko + j;
          float v = (k <= m2) ? av[j] * wv[j] : 0.f;
          if (k == m2) v += Dh * wiv[j];
          a[j] = (__bf16)v;
        }
#pragma unroll
        for (int pt = 0; pt < 4; ++pt)
          acc[1][pt] = __builtin_amdgcn_mfma_f32_16x16x32_bf16(a, bf[pt], acc[1][pt], 0, 0, 0);
      }
    }
  };

  auto inter = [&]() {
#pragma unroll
    for (int kf = 0; kf < 4; ++kf) {
      const int no = kf * 32 + qo;
      v8bf bf[4];
#pragma unroll
      for (int pt = 0; pt < 4; ++pt) {
        const float* pr = Pbase + (size_t)(pt * 16 + row) * 128 + no;
        bf[pt] = cvt8(*(const float4*)pr, *(const float4*)(pr + 4));
      }
      const v8bf a0 = cvt8(*(const float4*)(Cr0 + no), *(const float4*)(Cr0 + no + 4));
      const v8bf a1 = cvt8(*(const float4*)(Cr1 + no), *(const float4*)(Cr1 + no + 4));
#pragma unroll
      for (int pt = 0; pt < 4; ++pt) {
        acc[0][pt] = __builtin_amdgcn_mfma_f32_16x16x32_bf16(a0, bf[pt], acc[0][pt], 0, 0, 0);
        acc[1][pt] = __builtin_amdgcn_mfma_f32_16x16x32_bf16(a1, bf[pt], acc[1][pt], 0, 0, 0);
      }
    }
  };

  if (half == 0) {
    unsigned xr[16];
    xload(0, xr);
    xstore(xr, 0);
    __syncthreads();
    intra(0, 0);
    inter();
  } else {
    unsigned xr[16], xr2[16];
    xload(0, xr);
    xload(128, xr2);  // both tiles' global loads in flight before first wait
    xstore(xr, 0);
    __syncthreads();
    xstore(xr2, 1);   // writes buf1 while buf0 is being read
    intra(0, 0);
    __syncthreads();
    intra(128, 1);
    inter();
  }

  // ---- epilogue: scale by exp(dA[m]) and store ----
  // C/D layout: col = lane&15, row = (lane>>4)*4 + reg
  float* Obase = outp + ((size_t)(b * 4096 + c * 256) * 32 + h) * 64;
  const int rbase = q * 4;
  const float4 e0 = *(const float4*)(dAp + base_hc + ws + rbase);        // mt0 rows
  const float4 e1 = *(const float4*)(dAp + base_hc + ws + 16 + rbase);   // mt1 rows
  const float ev[2][4] = {{e0.x, e0.y, e0.z, e0.w}, {e1.x, e1.y, e1.z, e1.w}};
#pragma unroll
  for (int mt = 0; mt < 2; ++mt) {
#pragma unroll
    for (int r = 0; r < 4; ++r) {
      const int m = ws + mt * 16 + rbase + r;
      const float e = __expf(ev[mt][r]);
      float* orow = Obase + (size_t)m * 2048;
#pragma unroll
      for (int pt = 0; pt < 4; ++pt)
        orow[pt * 16 + row] = acc[mt][pt][r] * e;
    }
  }
}

extern "C" void kernel_launch(void* const* d_in, const int* in_sizes, int n_in,
                              void* d_out, int out_size, void* d_ws, size_t ws_size,
                              hipStream_t stream) {
  const float* cb = (const float*)d_in[0];
  const float* x = (const float*)d_in[1];
  const float* dt = (const float*)d_in[2];
  const float* dA = (const float*)d_in[3];
  const float* C = (const float*)d_in[4];
  const float* pv = (const float*)d_in[5];
  const float* D = (const float*)d_in[6];
  float* out = (float*)d_out;
  // grid 2048: h fastest (cb/C L2 reuse), then m-half (x/prev reuse), then c, b
  mamba_cs_kernel<<<dim3(2048), dim3(256), 0, stream>>>(cb, x, dt, dA, C, pv, D, out);
}